// Round 19
// baseline (115.394 us; speedup 1.0000x reference)
//
#include <hip/hip_runtime.h>
#include <hip/hip_bf16.h>

#define N_HALF 4096
#define M_TOT  8192
#define K_DIM  256
#define NBLK   512     // persistent mmd blocks (2 per CU)
#define NPACK  512     // pack blocks (2 per CU)

// ws layout (bytes)
#define WS_SQ      0                       // 8192 f32 (32 KB)
#define WS_COLPART 32768                   // 512*256 f32 (512 KB)
#define WS_SQD     557056                  // 512 f64 (4 KB)
#define WS_BAND    561152                  // f64
#define WS_CNT     561160                  // u32 (k_mmd completion)
#define WS_PCNT    561164                  // u32 (band-ready flag)
#define WS_PARTS   561216                  // 512 f64 (4 KB)
#define WS_P       565504                  // 8192*256 bf16 = 4 MB

typedef __attribute__((ext_vector_type(8))) short short8;
typedef __attribute__((ext_vector_type(4))) float f32x4;

__device__ __forceinline__ void gload16(const void* g, void* l) {
    __builtin_amdgcn_global_load_lds(
        (const __attribute__((address_space(1))) void*)g,
        (__attribute__((address_space(3))) void*)l, 16, 0, 0);
}

__device__ __forceinline__ float rexp2(float x) {   // q in [-1,0]: raw op safe
    float r; asm("v_exp_f32 %0, %1" : "=v"(r) : "v"(x)); return r;
}

#define SB0   __builtin_amdgcn_sched_barrier(0)
#define BAR   __builtin_amdgcn_s_barrier()
#define VMC4  asm volatile("s_waitcnt vmcnt(4)" ::: "memory")
#define LGKM0 asm volatile("s_waitcnt lgkmcnt(0)" ::: "memory")

// ---- pure pack: bf16 + row sumsq + col partial sums (no tail, no handshake) ----
__global__ __launch_bounds__(256) void k_pack(const float* __restrict__ src,
        const float* __restrict__ tgt, ushort* __restrict__ P,
        float* __restrict__ sq, float* __restrict__ colpart,
        double* __restrict__ sqd) {
    __shared__ float  colred[4][256];
    __shared__ double sblk[4];
    int tid = threadIdx.x, w = tid >> 6, l = tid & 63;
    int blk = blockIdx.x;                       // 512 blocks x 16 rows
    float c0 = 0.f, c1 = 0.f, c2 = 0.f, c3 = 0.f;
    double sacc = 0.0;
#pragma unroll
    for (int j = 0; j < 4; ++j) {
        int row = (blk << 4) + (j << 2) + w;
        const float* base = (row < N_HALF) ? src + (size_t)row * K_DIM
                                           : tgt + (size_t)(row - N_HALF) * K_DIM;
        float4 v = *(const float4*)(base + (l << 2));
        __hip_bfloat16 b0 = __float2bfloat16(v.x), b1 = __float2bfloat16(v.y),
                       b2 = __float2bfloat16(v.z), b3 = __float2bfloat16(v.w);
        ushort4 hv = { *(ushort*)&b0, *(ushort*)&b1, *(ushort*)&b2, *(ushort*)&b3 };
        *(ushort4*)(P + (size_t)row * K_DIM + (l << 2)) = hv;
        float s = v.x * v.x + v.y * v.y + v.z * v.z + v.w * v.w;
#pragma unroll
        for (int off = 32; off > 0; off >>= 1) s += __shfl_down(s, off, 64);
        if (l == 0) { sq[row] = s; sacc += (double)s; }
        c0 += v.x; c1 += v.y; c2 += v.z; c3 += v.w;
    }
    *(float4*)&colred[w][l << 2] = make_float4(c0, c1, c2, c3);
    if (l == 0) sblk[w] = sacc;
    __syncthreads();
    colpart[(blk << 8) + tid] = colred[0][tid] + colred[1][tid] +
                                colred[2][tid] + colred[3][tid];
    if (tid == 0)
        sqd[blk] = sblk[0] + sblk[1] + sblk[2] + sblk[3];
}

// triangle decode over 64x64 grid: t -> (bi, bj), bi <= bj
__device__ __forceinline__ void tri_decode(int t, int& bi, int& bj) {
    int x = (int)(64.5 - sqrt(64.5 * 64.5 - 2.0 * (double)t));
    while (x * 64 - x * (x - 1) / 2 > t) --x;
    while ((x + 1) * 64 - (x + 1) * x / 2 <= t) ++x;
    bi = x; bj = x + (t - (x * 64 - x * (x - 1) / 2));
}

// stage one 128x64 panel (16 KB): 2 gload16 per thread
__device__ __forceinline__ void stagePanel(const ushort* srcbase, size_t soff,
                                           char* ldsbase, int ldst) {
#pragma unroll
    for (int p = 0; p < 2; ++p)
        gload16(srcbase + soff + ((size_t)(p << 6) * K_DIM),
                ldsbase + (p << 13) + ldst);
}

// one K-tile of compute: 2 kk sub-phases x (6 ds_read_b128 + 8 MFMA)
__device__ __forceinline__ void computeTile(const ushort (&A)[128][64],
        const ushort (&B)[128][64], const int (&aoff)[4], const int (&boff)[2],
        f32x4 (&acc)[4][2]) {
#pragma unroll
    for (int kk = 0; kk < 2; ++kk) {
        short8 af[4], bf[2];
#pragma unroll
        for (int mt = 0; mt < 4; ++mt)
            af[mt] = *(const short8*)((const char*)&A[0][0] + (aoff[mt] ^ (kk << 6)));
#pragma unroll
        for (int nt = 0; nt < 2; ++nt)
            bf[nt] = *(const short8*)((const char*)&B[0][0] + (boff[nt] ^ (kk << 6)));
        __builtin_amdgcn_s_setprio(1);
#pragma unroll
        for (int mt = 0; mt < 4; ++mt)
#pragma unroll
            for (int nt = 0; nt < 2; ++nt)
                acc[mt][nt] = __builtin_amdgcn_mfma_f32_16x16x32_bf16(
                    af[mt], bf[nt], acc[mt][nt], 0, 0, 0);
        __builtin_amdgcn_s_setprio(0);
    }
}

// ---- persistent fused MFMA (R12/R17 pipeline) + in-kernel stats block ----
__global__ __launch_bounds__(512, 4) void k_mmd(const ushort* __restrict__ P,
        const float* __restrict__ sq, const float* __restrict__ colpart,
        const double* __restrict__ sqd, double* __restrict__ band,
        double* __restrict__ parts, unsigned int* __restrict__ cnt,
        unsigned int* __restrict__ pcnt, float* __restrict__ out) {
    __shared__ ushort As[2][128][64];
    __shared__ ushort Bs[2][128][64];

    int b = blockIdx.x;
    int xcd = b & 7, jj = b >> 3;
    int ntiles = (jj < 4) ? 5 : 4;     // 260 tiles per XCD = 4*64 + 4

    int tid = threadIdx.x, lane = tid & 63, w = tid >> 6;
    int wr = w >> 2, wc = w & 3;       // 2 x 4 wave grid, wave-tile 64x32

    int cx = ((lane >> 4) ^ (lane & 7)) << 4;
    int aoff[4], boff[2];
#pragma unroll
    for (int mt = 0; mt < 4; ++mt)
        aoff[mt] = (((wr << 6) + (mt << 4) + (lane & 15)) << 7) + cx;
#pragma unroll
    for (int nt = 0; nt < 2; ++nt)
        boff[nt] = (((wc << 5) + (nt << 4) + (lane & 15)) << 7) + cx;

    size_t soff = (size_t)(tid >> 3) * K_DIM
                + (((tid & 7) ^ ((tid >> 3) & 7)) << 3);
    int ldst = tid << 4;

    // ---- designated stats block (4-tile block: off the 5-tile critical path)
    if (b == NBLK - 1) {
        double* dred = (double*)&As[0][0][0];   // 4 KB
        double* dcol = (double*)&Bs[0][0][0];   // 4 KB
        dred[tid] = sqd[tid];
        __syncthreads();
        for (int off = 256; off > 0; off >>= 1) {
            if (tid < off) dred[tid] += dred[tid + off];
            __syncthreads();
        }
        double Stot = dred[0];
        __syncthreads();
        int c = tid & 255, h = tid >> 8;        // 2 halves x 256 rows
        int r0 = h << 8;
        double e0 = 0.0, e1 = 0.0, e2 = 0.0, e3 = 0.0,
               e4 = 0.0, e5 = 0.0, e6 = 0.0, e7 = 0.0;
#pragma unroll 4
        for (int r = 0; r < 256; r += 8) {
            e0 += (double)colpart[((r0 + r + 0) << 8) + c];
            e1 += (double)colpart[((r0 + r + 1) << 8) + c];
            e2 += (double)colpart[((r0 + r + 2) << 8) + c];
            e3 += (double)colpart[((r0 + r + 3) << 8) + c];
            e4 += (double)colpart[((r0 + r + 4) << 8) + c];
            e5 += (double)colpart[((r0 + r + 5) << 8) + c];
            e6 += (double)colpart[((r0 + r + 6) << 8) + c];
            e7 += (double)colpart[((r0 + r + 7) << 8) + c];
        }
        dcol[(h << 8) + c] = ((e0 + e1) + (e2 + e3)) + ((e4 + e5) + (e6 + e7));
        __syncthreads();
        dred[tid] = 0.0;
        if (tid < 256) {
            double f = dcol[tid] + dcol[tid + 256];
            dred[tid] = f * f;
        }
        __syncthreads();
        for (int off = 256; off > 0; off >>= 1) {
            if (tid < off) dred[tid] += dred[tid + off];
            __syncthreads();
        }
        if (tid == 0) {
            double sum_d2 = 2.0 * (double)M_TOT * Stot - 2.0 * dred[0];
            *band = (sum_d2 / ((double)M_TOT * (double)M_TOT - (double)M_TOT))
                    * 0.25;
            __threadfence();
            atomicAdd(pcnt, 1u);               // band ready
        }
        __syncthreads();                        // LDS free again before staging
    }

    int cbi, cbj;
    tri_decode(xcd * 260 + jj, cbi, cbj);
    int row0 = cbi << 7, col0 = cbj << 7;
    const ushort* Pa = P + (size_t)row0 * K_DIM;
    const ushort* Pb = P + (size_t)col0 * K_DIM;

    f32x4 acc[4][2] = {};
    double bsum = 0.0;
    float E16 = 0.f, twoE16 = 0.f;              // set at k==0 (band-gated)

    stagePanel(Pa,      soff, (char*)&As[0][0][0], ldst);
    stagePanel(Pb,      soff, (char*)&Bs[0][0][0], ldst);
    stagePanel(Pa + 64, soff, (char*)&As[1][0][0], ldst);
    stagePanel(Pb + 64, soff, (char*)&Bs[1][0][0], ldst);

    for (int k = 0; k < ntiles; ++k) {
        bool more = (k + 1 < ntiles);
        SB0; VMC4; SB0; BAR; SB0;
        computeTile(As[0], Bs[0], aoff, boff, acc);
        SB0; LGKM0; SB0; BAR; SB0;
        stagePanel(Pa + 128, soff, (char*)&As[0][0][0], ldst);
        stagePanel(Pb + 128, soff, (char*)&Bs[0][0][0], ldst);
        SB0; VMC4; SB0; BAR; SB0;
        computeTile(As[1], Bs[1], aoff, boff, acc);
        SB0; LGKM0; SB0; BAR; SB0;
        stagePanel(Pa + 192, soff, (char*)&As[1][0][0], ldst);
        stagePanel(Pb + 192, soff, (char*)&Bs[1][0][0], ldst);
        SB0; VMC4; SB0; BAR; SB0;
        computeTile(As[0], Bs[0], aoff, boff, acc);
        SB0; LGKM0; SB0; BAR; SB0;
        // current-tile sq loads (retire before next-tile stages, in-order)
        float4 sv[4]; float bv0, bv1;
#pragma unroll
        for (int mt = 0; mt < 4; ++mt)
            sv[mt] = *(const float4*)&sq[row0 + (wr << 6) + (mt << 4) +
                                         ((lane >> 4) << 2)];
        bv0 = sq[col0 + (wc << 5) + (lane & 15)];
        bv1 = sq[col0 + (wc << 5) + 16 + (lane & 15)];
        int nbi = cbi, nbj = cbj, nrow0 = row0, ncol0 = col0;
        const ushort *nPa = Pa, *nPb = Pb;
        if (more) {
            tri_decode(xcd * 260 + jj + ((k + 1) << 6), nbi, nbj);
            nrow0 = nbi << 7; ncol0 = nbj << 7;
            nPa = P + (size_t)nrow0 * K_DIM;
            nPb = P + (size_t)ncol0 * K_DIM;
            stagePanel(nPa, soff, (char*)&As[0][0][0], ldst);
            stagePanel(nPb, soff, (char*)&Bs[0][0][0], ldst);
        }
        SB0; VMC4; SB0; BAR; SB0;
        computeTile(As[1], Bs[1], aoff, boff, acc);
        SB0; LGKM0; SB0; BAR; SB0;
        if (more) {
            stagePanel(nPa + 64, soff, (char*)&As[1][0][0], ldst);
            stagePanel(nPb + 64, soff, (char*)&Bs[1][0][0], ldst);
        }
        // ---- first epilogue: acquire band (stats long since done) ----
        if (k == 0) {
            if (tid == 0)
                while (atomicAdd(pcnt, 0u) == 0u) __builtin_amdgcn_s_sleep(8);
            __syncthreads();
            __threadfence();
            double bwd = *(volatile const double*)band;
            E16 = (float)(1.4426950408889634 / (bwd * 16.0));
            twoE16 = 2.f * E16;
        }
        // epilogue (overlaps next tile's in-flight loads)
        bool isdiag = (cbi == cbj);
        float p0 = 0.f, p1 = 0.f, p2 = 0.f, p3 = 0.f, p4 = 0.f;
#pragma unroll
        for (int mt = 0; mt < 4; ++mt) {
            float A4[4] = { -sv[mt].x * E16, -sv[mt].y * E16,
                            -sv[mt].z * E16, -sv[mt].w * E16 };
            int rlb = (wr << 6) + (mt << 4) + ((lane >> 4) << 2);
#pragma unroll
            for (int nt = 0; nt < 2; ++nt) {
                float bvn = -(nt ? bv1 : bv0) * E16;
                int cl = (wc << 5) + (nt << 4) + (lane & 15);
#pragma unroll
                for (int j = 0; j < 4; ++j) {
                    float q = fmaf(acc[mt][nt][j], twoE16, A4[j] + bvn);
                    if (isdiag && (rlb + j == cl)) q = 0.f;
                    float t4 = rexp2(q);
                    float t3 = t4 * t4, t2 = t3 * t3, t1 = t2 * t2, t0 = t1 * t1;
                    p4 += t4; p3 += t3; p2 += t2; p1 += t1; p0 += t0;
                }
            }
        }
        float part = (p0 + p1) + (p2 + p3) + p4;
        float sgn = ((row0 < N_HALF) == (col0 < N_HALF)) ? 1.f : -1.f;
        float wt  = isdiag ? 1.f : 2.f;
        bsum += (double)part * (double)(sgn * wt);
#pragma unroll
        for (int mt = 0; mt < 4; ++mt)
#pragma unroll
            for (int nt = 0; nt < 2; ++nt)
                acc[mt][nt] = (f32x4){0.f, 0.f, 0.f, 0.f};
        cbi = nbi; cbj = nbj; row0 = nrow0; col0 = ncol0; Pa = nPa; Pb = nPb;
    }

    // wave reduce bsum (double)
#pragma unroll
    for (int off = 32; off > 0; off >>= 1) bsum += __shfl_down(bsum, off, 64);

    __syncthreads();                    // LDS dead: reuse
    double* wpart = (double*)&As[0][0][0];
    int*    lastf = (int*)((char*)&As[0][0][0] + 128);
    double* dredm = (double*)&Bs[0][0][0];

    if (lane == 0) wpart[w] = bsum;
    __syncthreads();
    if (tid == 0) {
        double tot = 0.0;
#pragma unroll
        for (int i = 0; i < 8; ++i) tot += wpart[i];
        parts[b] = tot;
        __threadfence();
        unsigned int o = atomicAdd(cnt, 1u);
        *lastf = (o == NBLK - 1u);
    }
    __syncthreads();
    if (*lastf) {                      // last block: reduce all partials
        __threadfence();
        dredm[tid] = parts[tid];
        __syncthreads();
        for (int off = 256; off > 0; off >>= 1) {
            if (tid < off) dredm[tid] += dredm[tid + off];
            __syncthreads();
        }
        if (tid == 0)
            out[0] = (float)(dredm[0] * (1.0 / ((double)N_HALF * (double)N_HALF)));
    }
}

extern "C" void kernel_launch(void* const* d_in, const int* in_sizes, int n_in,
                              void* d_out, int out_size, void* d_ws, size_t ws_size,
                              hipStream_t stream) {
    const float* src = (const float*)d_in[0];
    const float* tgt = (const float*)d_in[1];
    float*  sq      = (float*)((char*)d_ws + WS_SQ);
    float*  colpart = (float*)((char*)d_ws + WS_COLPART);
    double* sqd     = (double*)((char*)d_ws + WS_SQD);
    double* band    = (double*)((char*)d_ws + WS_BAND);
    unsigned int* cnt  = (unsigned int*)((char*)d_ws + WS_CNT);
    unsigned int* pcnt = (unsigned int*)((char*)d_ws + WS_PCNT);
    double* parts   = (double*)((char*)d_ws + WS_PARTS);
    ushort* P       = (ushort*)((char*)d_ws + WS_P);

    hipMemsetAsync((char*)d_ws + WS_BAND, 0, 64, stream);
    k_pack <<<NPACK, 256, 0, stream>>>(src, tgt, P, sq, colpart, sqd);
    k_mmd  <<<NBLK,  512, 0, stream>>>(P, sq, colpart, sqd, band,
                                       parts, cnt, pcnt, (float*)d_out);
}

// Round 20
// 71.140 us; speedup vs baseline: 1.6221x; 1.6221x over previous
//
#include <hip/hip_runtime.h>
#include <hip/hip_bf16.h>

#define N_HALF 4096
#define M_TOT  8192
#define K_DIM  256
#define NBLK   512     // persistent mmd blocks (2 per CU)
#define NPACK  256     // pack blocks

// ws layout (bytes)
#define WS_SQ      0                       // 8192 f32 (32 KB)
#define WS_COLPART 32768                   // 256*256 f32 (256 KB)
#define WS_SQD     294912                  // 256 f64 (2 KB)
#define WS_BAND    296960                  // f64
#define WS_CNT     296968                  // u32 (k_mmd completion)
#define WS_PCNT    296972                  // u32 (k_pack completion)
#define WS_PARTS   297024                  // 512 f64 (4 KB)
#define WS_P       313856                  // 8192*256 bf16 = 4 MB

typedef __attribute__((ext_vector_type(8))) short short8;
typedef __attribute__((ext_vector_type(4))) float f32x4;

__device__ __forceinline__ void gload16(const void* g, void* l) {
    __builtin_amdgcn_global_load_lds(
        (const __attribute__((address_space(1))) void*)g,
        (__attribute__((address_space(3))) void*)l, 16, 0, 0);
}

__device__ __forceinline__ float rexp2(float x) {   // q in [-1,0]: raw op safe
    float r; asm("v_exp_f32 %0, %1" : "=v"(r) : "v"(x)); return r;
}

#define SB0   __builtin_amdgcn_sched_barrier(0)
#define BAR   __builtin_amdgcn_s_barrier()
#define VMC4  asm volatile("s_waitcnt vmcnt(4)" ::: "memory")
#define LGKM0 asm volatile("s_waitcnt lgkmcnt(0)" ::: "memory")

// ---- pack bf16 + row sumsq + col partial sums + (last block) bandwidth ----
// 256 blocks x 512 thr (32 rows each); stats tail parallel: 2 halves x 8 chains.
__global__ __launch_bounds__(512) void k_pack(const float* __restrict__ src,
        const float* __restrict__ tgt, ushort* __restrict__ P,
        float* __restrict__ sq, float* __restrict__ colpart,
        double* __restrict__ sqd, double* __restrict__ band,
        unsigned int* __restrict__ pcnt) {
    __shared__ float  colred[8][256];
    __shared__ double sblk[8];
    __shared__ double dred[512];
    __shared__ double dcol[2][256];
    __shared__ int    lastf;
    int tid = threadIdx.x, w = tid >> 6, l = tid & 63;
    int blk = blockIdx.x;                       // 256 blocks x 32 rows
    float c0 = 0.f, c1 = 0.f, c2 = 0.f, c3 = 0.f;
    double sacc = 0.0;
#pragma unroll
    for (int j = 0; j < 4; ++j) {
        int row = (blk << 5) + (j << 3) + w;
        const float* base = (row < N_HALF) ? src + (size_t)row * K_DIM
                                           : tgt + (size_t)(row - N_HALF) * K_DIM;
        float4 v = *(const float4*)(base + (l << 2));
        __hip_bfloat16 b0 = __float2bfloat16(v.x), b1 = __float2bfloat16(v.y),
                       b2 = __float2bfloat16(v.z), b3 = __float2bfloat16(v.w);
        ushort4 hv = { *(ushort*)&b0, *(ushort*)&b1, *(ushort*)&b2, *(ushort*)&b3 };
        *(ushort4*)(P + (size_t)row * K_DIM + (l << 2)) = hv;
        float s = v.x * v.x + v.y * v.y + v.z * v.z + v.w * v.w;
#pragma unroll
        for (int off = 32; off > 0; off >>= 1) s += __shfl_down(s, off, 64);
        if (l == 0) { sq[row] = s; sacc += (double)s; }
        c0 += v.x; c1 += v.y; c2 += v.z; c3 += v.w;
    }
    *(float4*)&colred[w][l << 2] = make_float4(c0, c1, c2, c3);
    if (l == 0) sblk[w] = sacc;
    __syncthreads();
    if (tid < 256) {
        float ts = 0.f;
#pragma unroll
        for (int ww = 0; ww < 8; ++ww) ts += colred[ww][tid];
        colpart[(blk << 8) + tid] = ts;
    }
    if (tid == 0) {
        double td = 0.0;
#pragma unroll
        for (int ww = 0; ww < 8; ++ww) td += sblk[ww];
        sqd[blk] = td;
    }
    __syncthreads();                  // all global writes issued
    if (tid == 0) {
        __threadfence();
        unsigned int o = atomicAdd(pcnt, 1u);
        lastf = (o == NPACK - 1u);
    }
    __syncthreads();
    if (lastf) {                      // folded bandwidth computation (parallel)
        __threadfence();
        // Stot over sqd[256]
        dred[tid] = (tid < 256) ? sqd[tid] : 0.0;
        __syncthreads();
        for (int off = 256; off > 0; off >>= 1) {
            if (tid < off) dred[tid] += dred[tid + off];
            __syncthreads();
        }
        double Stot = dred[0];
        __syncthreads();
        // colsum: col = tid&255, half h = tid>>8 covers 128 b-rounds, 8 chains
        int c = tid & 255, h = tid >> 8;
        int b0i = h << 7;
        double e0 = 0.0, e1 = 0.0, e2 = 0.0, e3 = 0.0,
               e4 = 0.0, e5 = 0.0, e6 = 0.0, e7 = 0.0;
#pragma unroll 4
        for (int b = 0; b < 128; b += 8) {
            e0 += (double)colpart[((b0i + b + 0) << 8) + c];
            e1 += (double)colpart[((b0i + b + 1) << 8) + c];
            e2 += (double)colpart[((b0i + b + 2) << 8) + c];
            e3 += (double)colpart[((b0i + b + 3) << 8) + c];
            e4 += (double)colpart[((b0i + b + 4) << 8) + c];
            e5 += (double)colpart[((b0i + b + 5) << 8) + c];
            e6 += (double)colpart[((b0i + b + 6) << 8) + c];
            e7 += (double)colpart[((b0i + b + 7) << 8) + c];
        }
        dcol[h][c] = ((e0 + e1) + (e2 + e3)) + ((e4 + e5) + (e6 + e7));
        __syncthreads();
        dred[tid] = 0.0;
        if (tid < 256) {
            double f = dcol[0][tid] + dcol[1][tid];
            dred[tid] = f * f;
        }
        __syncthreads();
        for (int off = 256; off > 0; off >>= 1) {
            if (tid < off) dred[tid] += dred[tid + off];
            __syncthreads();
        }
        if (tid == 0) {
            double sum_d2 = 2.0 * (double)M_TOT * Stot - 2.0 * dred[0];
            double bw = sum_d2 / ((double)M_TOT * (double)M_TOT - (double)M_TOT);
            *band = bw * 0.25;
        }
    }
}

// triangle decode over 64x64 grid: t -> (bi, bj), bi <= bj
__device__ __forceinline__ void tri_decode(int t, int& bi, int& bj) {
    int x = (int)(64.5 - sqrt(64.5 * 64.5 - 2.0 * (double)t));
    while (x * 64 - x * (x - 1) / 2 > t) --x;
    while ((x + 1) * 64 - (x + 1) * x / 2 <= t) ++x;
    bi = x; bj = x + (t - (x * 64 - x * (x - 1) / 2));
}

// stage one 128x64 panel (16 KB): 2 gload16 per thread
__device__ __forceinline__ void stagePanel(const ushort* srcbase, size_t soff,
                                           char* ldsbase, int ldst) {
#pragma unroll
    for (int p = 0; p < 2; ++p)
        gload16(srcbase + soff + ((size_t)(p << 6) * K_DIM),
                ldsbase + (p << 13) + ldst);
}

// one K-tile of compute: 2 kk sub-phases x (6 ds_read_b128 + 8 MFMA)
__device__ __forceinline__ void computeTile(const ushort (&A)[128][64],
        const ushort (&B)[128][64], const int (&aoff)[4], const int (&boff)[2],
        f32x4 (&acc)[4][2]) {
#pragma unroll
    for (int kk = 0; kk < 2; ++kk) {
        short8 af[4], bf[2];
#pragma unroll
        for (int mt = 0; mt < 4; ++mt)
            af[mt] = *(const short8*)((const char*)&A[0][0] + (aoff[mt] ^ (kk << 6)));
#pragma unroll
        for (int nt = 0; nt < 2; ++nt)
            bf[nt] = *(const short8*)((const char*)&B[0][0] + (boff[nt] ^ (kk << 6)));
        __builtin_amdgcn_s_setprio(1);
#pragma unroll
        for (int mt = 0; mt < 4; ++mt)
#pragma unroll
            for (int nt = 0; nt < 2; ++nt)
                acc[mt][nt] = __builtin_amdgcn_mfma_f32_16x16x32_bf16(
                    af[mt], bf[nt], acc[mt][nt], 0, 0, 0);
        __builtin_amdgcn_s_setprio(0);
    }
}

// ---- persistent fused MFMA: 512 blocks x 4-5 tiles, continuous pipeline ----
// (verbatim R12/R17 structure: best measured k_mmd = 43-50 us)
__global__ __launch_bounds__(512, 4) void k_mmd(const ushort* __restrict__ P,
        const float* __restrict__ sq, const double* __restrict__ band,
        double* __restrict__ parts, unsigned int* __restrict__ cnt,
        float* __restrict__ out) {
    __shared__ ushort As[2][128][64];
    __shared__ ushort Bs[2][128][64];

    int b = blockIdx.x;
    int xcd = b & 7, jj = b >> 3;
    int ntiles = (jj < 4) ? 5 : 4;     // 260 tiles per XCD = 4*64 + 4

    int tid = threadIdx.x, lane = tid & 63, w = tid >> 6;
    int wr = w >> 2, wc = w & 3;       // 2 x 4 wave grid, wave-tile 64x32

    int cx = ((lane >> 4) ^ (lane & 7)) << 4;
    int aoff[4], boff[2];
#pragma unroll
    for (int mt = 0; mt < 4; ++mt)
        aoff[mt] = (((wr << 6) + (mt << 4) + (lane & 15)) << 7) + cx;
#pragma unroll
    for (int nt = 0; nt < 2; ++nt)
        boff[nt] = (((wc << 5) + (nt << 4) + (lane & 15)) << 7) + cx;

    size_t soff = (size_t)(tid >> 3) * K_DIM
                + (((tid & 7) ^ ((tid >> 3) & 7)) << 3);
    int ldst = tid << 4;

    double bwd = *band;                       // oldest vmem; drained early
    float E16 = (float)(1.4426950408889634 / (bwd * 16.0));
    float twoE16 = 2.f * E16;

    int cbi, cbj;
    tri_decode(xcd * 260 + jj, cbi, cbj);
    int row0 = cbi << 7, col0 = cbj << 7;
    const ushort* Pa = P + (size_t)row0 * K_DIM;
    const ushort* Pb = P + (size_t)col0 * K_DIM;

    f32x4 acc[4][2] = {};
    double bsum = 0.0;

    stagePanel(Pa,      soff, (char*)&As[0][0][0], ldst);
    stagePanel(Pb,      soff, (char*)&Bs[0][0][0], ldst);
    stagePanel(Pa + 64, soff, (char*)&As[1][0][0], ldst);
    stagePanel(Pb + 64, soff, (char*)&Bs[1][0][0], ldst);

    for (int k = 0; k < ntiles; ++k) {
        bool more = (k + 1 < ntiles);
        SB0; VMC4; SB0; BAR; SB0;
        computeTile(As[0], Bs[0], aoff, boff, acc);
        SB0; LGKM0; SB0; BAR; SB0;
        stagePanel(Pa + 128, soff, (char*)&As[0][0][0], ldst);
        stagePanel(Pb + 128, soff, (char*)&Bs[0][0][0], ldst);
        SB0; VMC4; SB0; BAR; SB0;
        computeTile(As[1], Bs[1], aoff, boff, acc);
        SB0; LGKM0; SB0; BAR; SB0;
        stagePanel(Pa + 192, soff, (char*)&As[1][0][0], ldst);
        stagePanel(Pb + 192, soff, (char*)&Bs[1][0][0], ldst);
        SB0; VMC4; SB0; BAR; SB0;
        computeTile(As[0], Bs[0], aoff, boff, acc);
        SB0; LGKM0; SB0; BAR; SB0;
        // current-tile sq loads (retire before next-tile stages, in-order)
        float4 sv[4]; float bv0, bv1;
#pragma unroll
        for (int mt = 0; mt < 4; ++mt)
            sv[mt] = *(const float4*)&sq[row0 + (wr << 6) + (mt << 4) +
                                         ((lane >> 4) << 2)];
        bv0 = sq[col0 + (wc << 5) + (lane & 15)];
        bv1 = sq[col0 + (wc << 5) + 16 + (lane & 15)];
        int nbi = cbi, nbj = cbj, nrow0 = row0, ncol0 = col0;
        const ushort *nPa = Pa, *nPb = Pb;
        if (more) {
            tri_decode(xcd * 260 + jj + ((k + 1) << 6), nbi, nbj);
            nrow0 = nbi << 7; ncol0 = nbj << 7;
            nPa = P + (size_t)nrow0 * K_DIM;
            nPb = P + (size_t)ncol0 * K_DIM;
            stagePanel(nPa, soff, (char*)&As[0][0][0], ldst);
            stagePanel(nPb, soff, (char*)&Bs[0][0][0], ldst);
        }
        SB0; VMC4; SB0; BAR; SB0;
        computeTile(As[1], Bs[1], aoff, boff, acc);
        SB0; LGKM0; SB0; BAR; SB0;
        if (more) {
            stagePanel(nPa + 64, soff, (char*)&As[1][0][0], ldst);
            stagePanel(nPb + 64, soff, (char*)&Bs[1][0][0], ldst);
        }
        // epilogue (overlaps next tile's in-flight loads)
        bool isdiag = (cbi == cbj);
        float p0 = 0.f, p1 = 0.f, p2 = 0.f, p3 = 0.f, p4 = 0.f;
#pragma unroll
        for (int mt = 0; mt < 4; ++mt) {
            float A4[4] = { -sv[mt].x * E16, -sv[mt].y * E16,
                            -sv[mt].z * E16, -sv[mt].w * E16 };
            int rlb = (wr << 6) + (mt << 4) + ((lane >> 4) << 2);
#pragma unroll
            for (int nt = 0; nt < 2; ++nt) {
                float bvn = -(nt ? bv1 : bv0) * E16;
                int cl = (wc << 5) + (nt << 4) + (lane & 15);
#pragma unroll
                for (int j = 0; j < 4; ++j) {
                    float q = fmaf(acc[mt][nt][j], twoE16, A4[j] + bvn);
                    if (isdiag && (rlb + j == cl)) q = 0.f;
                    float t4 = rexp2(q);
                    float t3 = t4 * t4, t2 = t3 * t3, t1 = t2 * t2, t0 = t1 * t1;
                    p4 += t4; p3 += t3; p2 += t2; p1 += t1; p0 += t0;
                }
            }
        }
        float part = (p0 + p1) + (p2 + p3) + p4;
        float sgn = ((row0 < N_HALF) == (col0 < N_HALF)) ? 1.f : -1.f;
        float wt  = isdiag ? 1.f : 2.f;
        bsum += (double)part * (double)(sgn * wt);
#pragma unroll
        for (int mt = 0; mt < 4; ++mt)
#pragma unroll
            for (int nt = 0; nt < 2; ++nt)
                acc[mt][nt] = (f32x4){0.f, 0.f, 0.f, 0.f};
        cbi = nbi; cbj = nbj; row0 = nrow0; col0 = ncol0; Pa = nPa; Pb = nPb;
    }

    // wave reduce bsum (double)
#pragma unroll
    for (int off = 32; off > 0; off >>= 1) bsum += __shfl_down(bsum, off, 64);

    __syncthreads();                    // LDS dead: reuse
    double* wpart = (double*)&As[0][0][0];
    int*    lastf = (int*)((char*)&As[0][0][0] + 128);
    double* dredm = (double*)&Bs[0][0][0];

    if (lane == 0) wpart[w] = bsum;
    __syncthreads();
    if (tid == 0) {
        double tot = 0.0;
#pragma unroll
        for (int i = 0; i < 8; ++i) tot += wpart[i];
        parts[b] = tot;
        __threadfence();
        unsigned int o = atomicAdd(cnt, 1u);
        *lastf = (o == NBLK - 1u);
    }
    __syncthreads();
    if (*lastf) {                      // last block: reduce all partials
        __threadfence();
        dredm[tid] = parts[tid];
        __syncthreads();
        for (int off = 256; off > 0; off >>= 1) {
            if (tid < off) dredm[tid] += dredm[tid + off];
            __syncthreads();
        }
        if (tid == 0)
            out[0] = (float)(dredm[0] * (1.0 / ((double)N_HALF * (double)N_HALF)));
    }
}

extern "C" void kernel_launch(void* const* d_in, const int* in_sizes, int n_in,
                              void* d_out, int out_size, void* d_ws, size_t ws_size,
                              hipStream_t stream) {
    const float* src = (const float*)d_in[0];
    const float* tgt = (const float*)d_in[1];
    float*  sq      = (float*)((char*)d_ws + WS_SQ);
    float*  colpart = (float*)((char*)d_ws + WS_COLPART);
    double* sqd     = (double*)((char*)d_ws + WS_SQD);
    double* band    = (double*)((char*)d_ws + WS_BAND);
    unsigned int* cnt  = (unsigned int*)((char*)d_ws + WS_CNT);
    unsigned int* pcnt = (unsigned int*)((char*)d_ws + WS_PCNT);
    double* parts   = (double*)((char*)d_ws + WS_PARTS);
    ushort* P       = (ushort*)((char*)d_ws + WS_P);

    hipMemsetAsync((char*)d_ws + WS_BAND, 0, 64, stream);
    k_pack <<<NPACK, 512, 0, stream>>>(src, tgt, P, sq, colpart, sqd, band, pcnt);
    k_mmd  <<<NBLK,  512, 0, stream>>>(P, sq, band, parts, cnt, (float*)d_out);
}

// Round 21
// 65.466 us; speedup vs baseline: 1.7627x; 1.0867x over previous
//
#include <hip/hip_runtime.h>
#include <hip/hip_bf16.h>

#define N_HALF 4096
#define M_TOT  8192
#define K_DIM  256
#define NBLK   512     // persistent mmd blocks (2 per CU)
#define NPACK  512     // pack blocks

// ws layout (bytes)
#define WS_SQ      0                       // 8192 f32 (32 KB)
#define WS_COLPART 32768                   // 512*256 f32 (512 KB)
#define WS_SQD     557056                  // 512 f64 (4 KB)
#define WS_COLSD   561152                  // 16*256 f64 (32 KB)
#define WS_BAND    593920                  // f64
#define WS_CNT     593928                  // u32 (k_mmd completion)
#define WS_PARTS   593984                  // 512 f64 (4 KB)
#define WS_P       598080                  // 8192*256 bf16 = 4 MB

typedef __attribute__((ext_vector_type(8))) short short8;
typedef __attribute__((ext_vector_type(4))) float f32x4;

__device__ __forceinline__ void gload16(const void* g, void* l) {
    __builtin_amdgcn_global_load_lds(
        (const __attribute__((address_space(1))) void*)g,
        (__attribute__((address_space(3))) void*)l, 16, 0, 0);
}

__device__ __forceinline__ float rexp2(float x) {   // q in [-1,0]: raw op safe
    float r; asm("v_exp_f32 %0, %1" : "=v"(r) : "v"(x)); return r;
}

#define SB0   __builtin_amdgcn_sched_barrier(0)
#define BAR   __builtin_amdgcn_s_barrier()
#define VMC4  asm volatile("s_waitcnt vmcnt(4)" ::: "memory")
#define LGKM0 asm volatile("s_waitcnt lgkmcnt(0)" ::: "memory")

// ---- pure pack: bf16 + row sumsq + col partial sums (no handshake) ----
__global__ __launch_bounds__(256) void k_pack(const float* __restrict__ src,
        const float* __restrict__ tgt, ushort* __restrict__ P,
        float* __restrict__ sq, float* __restrict__ colpart,
        double* __restrict__ sqd) {
    __shared__ float  colred[4][256];
    __shared__ double sblk[4];
    int tid = threadIdx.x, w = tid >> 6, l = tid & 63;
    int blk = blockIdx.x;                       // 512 blocks x 16 rows
    float c0 = 0.f, c1 = 0.f, c2 = 0.f, c3 = 0.f;
    double sacc = 0.0;
#pragma unroll
    for (int j = 0; j < 4; ++j) {
        int row = (blk << 4) + (j << 2) + w;
        const float* base = (row < N_HALF) ? src + (size_t)row * K_DIM
                                           : tgt + (size_t)(row - N_HALF) * K_DIM;
        float4 v = *(const float4*)(base + (l << 2));
        __hip_bfloat16 b0 = __float2bfloat16(v.x), b1 = __float2bfloat16(v.y),
                       b2 = __float2bfloat16(v.z), b3 = __float2bfloat16(v.w);
        ushort4 hv = { *(ushort*)&b0, *(ushort*)&b1, *(ushort*)&b2, *(ushort*)&b3 };
        *(ushort4*)(P + (size_t)row * K_DIM + (l << 2)) = hv;
        float s = v.x * v.x + v.y * v.y + v.z * v.z + v.w * v.w;
#pragma unroll
        for (int off = 32; off > 0; off >>= 1) s += __shfl_down(s, off, 64);
        if (l == 0) { sq[row] = s; sacc += (double)s; }
        c0 += v.x; c1 += v.y; c2 += v.z; c3 += v.w;
    }
    *(float4*)&colred[w][l << 2] = make_float4(c0, c1, c2, c3);
    if (l == 0) sblk[w] = sacc;
    __syncthreads();
    colpart[(blk << 8) + tid] = colred[0][tid] + colred[1][tid] +
                                colred[2][tid] + colred[3][tid];
    if (tid == 0)
        sqd[blk] = sblk[0] + sblk[1] + sblk[2] + sblk[3];
}

// ---- stage-1 column reduce: colpart[512][256] -> colsd[16][256] (f64) ----
__global__ __launch_bounds__(256) void k_cred(const float* __restrict__ colpart,
                                              double* __restrict__ colsd) {
    int c = threadIdx.x;                // column
    int i = blockIdx.x;                 // row group: 32 rows
    int r0 = i << 5;
    double e0 = 0.0, e1 = 0.0, e2 = 0.0, e3 = 0.0;
#pragma unroll
    for (int r = 0; r < 32; r += 4) {
        e0 += (double)colpart[((r0 + r + 0) << 8) + c];
        e1 += (double)colpart[((r0 + r + 1) << 8) + c];
        e2 += (double)colpart[((r0 + r + 2) << 8) + c];
        e3 += (double)colpart[((r0 + r + 3) << 8) + c];
    }
    colsd[(i << 8) + c] = (e0 + e1) + (e2 + e3);
}

// ---- stage-2: Stot + ||colsum||^2 -> bandwidth ----
__global__ __launch_bounds__(512) void k_stats(const double* __restrict__ sqd,
        const double* __restrict__ colsd, double* __restrict__ band) {
    __shared__ double dred[512];
    __shared__ double dcol[2][256];
    int tid = threadIdx.x;
    // Stot over sqd[512]
    dred[tid] = sqd[tid];
    __syncthreads();
    for (int off = 256; off > 0; off >>= 1) {
        if (tid < off) dred[tid] += dred[tid + off];
        __syncthreads();
    }
    double Stot = dred[0];
    __syncthreads();
    // colsum: col = tid&255, half h = tid>>8 sums 8 of the 16 groups
    int c = tid & 255, h = tid >> 8;
    double e0 = 0.0, e1 = 0.0, e2 = 0.0, e3 = 0.0;
#pragma unroll
    for (int i = 0; i < 8; i += 4) {
        e0 += colsd[(((h << 3) + i + 0) << 8) + c];
        e1 += colsd[(((h << 3) + i + 1) << 8) + c];
        e2 += colsd[(((h << 3) + i + 2) << 8) + c];
        e3 += colsd[(((h << 3) + i + 3) << 8) + c];
    }
    dcol[h][c] = (e0 + e1) + (e2 + e3);
    __syncthreads();
    dred[tid] = 0.0;
    if (tid < 256) {
        double f = dcol[0][tid] + dcol[1][tid];
        dred[tid] = f * f;
    }
    __syncthreads();
    for (int off = 256; off > 0; off >>= 1) {
        if (tid < off) dred[tid] += dred[tid + off];
        __syncthreads();
    }
    if (tid == 0) {
        double sum_d2 = 2.0 * (double)M_TOT * Stot - 2.0 * dred[0];
        double bw = sum_d2 / ((double)M_TOT * (double)M_TOT - (double)M_TOT);
        *band = bw * 0.25;
    }
}

// triangle decode over 64x64 grid: t -> (bi, bj), bi <= bj
__device__ __forceinline__ void tri_decode(int t, int& bi, int& bj) {
    int x = (int)(64.5 - sqrt(64.5 * 64.5 - 2.0 * (double)t));
    while (x * 64 - x * (x - 1) / 2 > t) --x;
    while ((x + 1) * 64 - (x + 1) * x / 2 <= t) ++x;
    bi = x; bj = x + (t - (x * 64 - x * (x - 1) / 2));
}

// stage one 128x64 panel (16 KB): 2 gload16 per thread
__device__ __forceinline__ void stagePanel(const ushort* srcbase, size_t soff,
                                           char* ldsbase, int ldst) {
#pragma unroll
    for (int p = 0; p < 2; ++p)
        gload16(srcbase + soff + ((size_t)(p << 6) * K_DIM),
                ldsbase + (p << 13) + ldst);
}

// one K-tile of compute: 2 kk sub-phases x (6 ds_read_b128 + 8 MFMA)
__device__ __forceinline__ void computeTile(const ushort (&A)[128][64],
        const ushort (&B)[128][64], const int (&aoff)[4], const int (&boff)[2],
        f32x4 (&acc)[4][2]) {
#pragma unroll
    for (int kk = 0; kk < 2; ++kk) {
        short8 af[4], bf[2];
#pragma unroll
        for (int mt = 0; mt < 4; ++mt)
            af[mt] = *(const short8*)((const char*)&A[0][0] + (aoff[mt] ^ (kk << 6)));
#pragma unroll
        for (int nt = 0; nt < 2; ++nt)
            bf[nt] = *(const short8*)((const char*)&B[0][0] + (boff[nt] ^ (kk << 6)));
        __builtin_amdgcn_s_setprio(1);
#pragma unroll
        for (int mt = 0; mt < 4; ++mt)
#pragma unroll
            for (int nt = 0; nt < 2; ++nt)
                acc[mt][nt] = __builtin_amdgcn_mfma_f32_16x16x32_bf16(
                    af[mt], bf[nt], acc[mt][nt], 0, 0, 0);
        __builtin_amdgcn_s_setprio(0);
    }
}

// ---- persistent fused MFMA: 512 blocks x 4-5 tiles, continuous pipeline ----
// (verbatim R12/R17/R20 structure: best measured k_mmd = 43-44 us)
__global__ __launch_bounds__(512, 4) void k_mmd(const ushort* __restrict__ P,
        const float* __restrict__ sq, const double* __restrict__ band,
        double* __restrict__ parts, unsigned int* __restrict__ cnt,
        float* __restrict__ out) {
    __shared__ ushort As[2][128][64];
    __shared__ ushort Bs[2][128][64];

    int b = blockIdx.x;
    int xcd = b & 7, jj = b >> 3;
    int ntiles = (jj < 4) ? 5 : 4;     // 260 tiles per XCD = 4*64 + 4

    int tid = threadIdx.x, lane = tid & 63, w = tid >> 6;
    int wr = w >> 2, wc = w & 3;       // 2 x 4 wave grid, wave-tile 64x32

    int cx = ((lane >> 4) ^ (lane & 7)) << 4;
    int aoff[4], boff[2];
#pragma unroll
    for (int mt = 0; mt < 4; ++mt)
        aoff[mt] = (((wr << 6) + (mt << 4) + (lane & 15)) << 7) + cx;
#pragma unroll
    for (int nt = 0; nt < 2; ++nt)
        boff[nt] = (((wc << 5) + (nt << 4) + (lane & 15)) << 7) + cx;

    size_t soff = (size_t)(tid >> 3) * K_DIM
                + (((tid & 7) ^ ((tid >> 3) & 7)) << 3);
    int ldst = tid << 4;

    double bwd = *band;                       // oldest vmem; drained early
    float E16 = (float)(1.4426950408889634 / (bwd * 16.0));
    float twoE16 = 2.f * E16;

    int cbi, cbj;
    tri_decode(xcd * 260 + jj, cbi, cbj);
    int row0 = cbi << 7, col0 = cbj << 7;
    const ushort* Pa = P + (size_t)row0 * K_DIM;
    const ushort* Pb = P + (size_t)col0 * K_DIM;

    f32x4 acc[4][2] = {};
    double bsum = 0.0;

    stagePanel(Pa,      soff, (char*)&As[0][0][0], ldst);
    stagePanel(Pb,      soff, (char*)&Bs[0][0][0], ldst);
    stagePanel(Pa + 64, soff, (char*)&As[1][0][0], ldst);
    stagePanel(Pb + 64, soff, (char*)&Bs[1][0][0], ldst);

    for (int k = 0; k < ntiles; ++k) {
        bool more = (k + 1 < ntiles);
        SB0; VMC4; SB0; BAR; SB0;
        computeTile(As[0], Bs[0], aoff, boff, acc);
        SB0; LGKM0; SB0; BAR; SB0;
        stagePanel(Pa + 128, soff, (char*)&As[0][0][0], ldst);
        stagePanel(Pb + 128, soff, (char*)&Bs[0][0][0], ldst);
        SB0; VMC4; SB0; BAR; SB0;
        computeTile(As[1], Bs[1], aoff, boff, acc);
        SB0; LGKM0; SB0; BAR; SB0;
        stagePanel(Pa + 192, soff, (char*)&As[1][0][0], ldst);
        stagePanel(Pb + 192, soff, (char*)&Bs[1][0][0], ldst);
        SB0; VMC4; SB0; BAR; SB0;
        computeTile(As[0], Bs[0], aoff, boff, acc);
        SB0; LGKM0; SB0; BAR; SB0;
        // current-tile sq loads (retire before next-tile stages, in-order)
        float4 sv[4]; float bv0, bv1;
#pragma unroll
        for (int mt = 0; mt < 4; ++mt)
            sv[mt] = *(const float4*)&sq[row0 + (wr << 6) + (mt << 4) +
                                         ((lane >> 4) << 2)];
        bv0 = sq[col0 + (wc << 5) + (lane & 15)];
        bv1 = sq[col0 + (wc << 5) + 16 + (lane & 15)];
        int nbi = cbi, nbj = cbj, nrow0 = row0, ncol0 = col0;
        const ushort *nPa = Pa, *nPb = Pb;
        if (more) {
            tri_decode(xcd * 260 + jj + ((k + 1) << 6), nbi, nbj);
            nrow0 = nbi << 7; ncol0 = nbj << 7;
            nPa = P + (size_t)nrow0 * K_DIM;
            nPb = P + (size_t)ncol0 * K_DIM;
            stagePanel(nPa, soff, (char*)&As[0][0][0], ldst);
            stagePanel(nPb, soff, (char*)&Bs[0][0][0], ldst);
        }
        SB0; VMC4; SB0; BAR; SB0;
        computeTile(As[1], Bs[1], aoff, boff, acc);
        SB0; LGKM0; SB0; BAR; SB0;
        if (more) {
            stagePanel(nPa + 64, soff, (char*)&As[1][0][0], ldst);
            stagePanel(nPb + 64, soff, (char*)&Bs[1][0][0], ldst);
        }
        // epilogue (overlaps next tile's in-flight loads)
        bool isdiag = (cbi == cbj);
        float p0 = 0.f, p1 = 0.f, p2 = 0.f, p3 = 0.f, p4 = 0.f;
#pragma unroll
        for (int mt = 0; mt < 4; ++mt) {
            float A4[4] = { -sv[mt].x * E16, -sv[mt].y * E16,
                            -sv[mt].z * E16, -sv[mt].w * E16 };
            int rlb = (wr << 6) + (mt << 4) + ((lane >> 4) << 2);
#pragma unroll
            for (int nt = 0; nt < 2; ++nt) {
                float bvn = -(nt ? bv1 : bv0) * E16;
                int cl = (wc << 5) + (nt << 4) + (lane & 15);
#pragma unroll
                for (int j = 0; j < 4; ++j) {
                    float q = fmaf(acc[mt][nt][j], twoE16, A4[j] + bvn);
                    if (isdiag && (rlb + j == cl)) q = 0.f;
                    float t4 = rexp2(q);
                    float t3 = t4 * t4, t2 = t3 * t3, t1 = t2 * t2, t0 = t1 * t1;
                    p4 += t4; p3 += t3; p2 += t2; p1 += t1; p0 += t0;
                }
            }
        }
        float part = (p0 + p1) + (p2 + p3) + p4;
        float sgn = ((row0 < N_HALF) == (col0 < N_HALF)) ? 1.f : -1.f;
        float wt  = isdiag ? 1.f : 2.f;
        bsum += (double)part * (double)(sgn * wt);
#pragma unroll
        for (int mt = 0; mt < 4; ++mt)
#pragma unroll
            for (int nt = 0; nt < 2; ++nt)
                acc[mt][nt] = (f32x4){0.f, 0.f, 0.f, 0.f};
        cbi = nbi; cbj = nbj; row0 = nrow0; col0 = ncol0; Pa = nPa; Pb = nPb;
    }

    // wave reduce bsum (double)
#pragma unroll
    for (int off = 32; off > 0; off >>= 1) bsum += __shfl_down(bsum, off, 64);

    __syncthreads();                    // LDS dead: reuse
    double* wpart = (double*)&As[0][0][0];
    int*    lastf = (int*)((char*)&As[0][0][0] + 128);
    double* dredm = (double*)&Bs[0][0][0];

    if (lane == 0) wpart[w] = bsum;
    __syncthreads();
    if (tid == 0) {
        double tot = 0.0;
#pragma unroll
        for (int i = 0; i < 8; ++i) tot += wpart[i];
        parts[b] = tot;
        __threadfence();
        unsigned int o = atomicAdd(cnt, 1u);
        *lastf = (o == NBLK - 1u);
    }
    __syncthreads();
    if (*lastf) {                      // last block: reduce all partials
        __threadfence();
        dredm[tid] = parts[tid];
        __syncthreads();
        for (int off = 256; off > 0; off >>= 1) {
            if (tid < off) dredm[tid] += dredm[tid + off];
            __syncthreads();
        }
        if (tid == 0)
            out[0] = (float)(dredm[0] * (1.0 / ((double)N_HALF * (double)N_HALF)));
    }
}

extern "C" void kernel_launch(void* const* d_in, const int* in_sizes, int n_in,
                              void* d_out, int out_size, void* d_ws, size_t ws_size,
                              hipStream_t stream) {
    const float* src = (const float*)d_in[0];
    const float* tgt = (const float*)d_in[1];
    float*  sq      = (float*)((char*)d_ws + WS_SQ);
    float*  colpart = (float*)((char*)d_ws + WS_COLPART);
    double* sqd     = (double*)((char*)d_ws + WS_SQD);
    double* colsd   = (double*)((char*)d_ws + WS_COLSD);
    double* band    = (double*)((char*)d_ws + WS_BAND);
    unsigned int* cnt = (unsigned int*)((char*)d_ws + WS_CNT);
    double* parts   = (double*)((char*)d_ws + WS_PARTS);
    ushort* P       = (ushort*)((char*)d_ws + WS_P);

    hipMemsetAsync((char*)d_ws + WS_BAND, 0, 64, stream);
    k_pack <<<NPACK, 256, 0, stream>>>(src, tgt, P, sq, colpart, sqd);
    k_cred <<<16,    256, 0, stream>>>(colpart, colsd);
    k_stats<<<1,     512, 0, stream>>>(sqd, colsd, band);
    k_mmd  <<<NBLK,  512, 0, stream>>>(P, sq, band, parts, cnt, (float*)d_out);
}

// Round 22
// 65.186 us; speedup vs baseline: 1.7702x; 1.0043x over previous
//
#include <hip/hip_runtime.h>
#include <hip/hip_bf16.h>

#define N_HALF 4096
#define M_TOT  8192
#define K_DIM  256
#define NBLK   512     // persistent mmd blocks (2 per CU)
#define NPACK  1024    // pack blocks (4 per CU)

// ws layout (bytes)
#define WS_SQ      0                       // 8192 f32 (32 KB)
#define WS_COLPART 32768                   // 1024*256 f32 (1 MB)
#define WS_SQD     1081344                 // 1024 f64 (8 KB)
#define WS_COLSD   1089536                 // 32*256 f64 (64 KB)
#define WS_BAND    1155072                 // f64
#define WS_CNT     1155080                 // u32 (k_mmd completion)
#define WS_PARTS   1155136                 // 512 f64 (4 KB)
#define WS_P       1159232                 // 8192*256 bf16 = 4 MB

typedef __attribute__((ext_vector_type(8))) short short8;
typedef __attribute__((ext_vector_type(4))) float f32x4;

__device__ __forceinline__ void gload16(const void* g, void* l) {
    __builtin_amdgcn_global_load_lds(
        (const __attribute__((address_space(1))) void*)g,
        (__attribute__((address_space(3))) void*)l, 16, 0, 0);
}

__device__ __forceinline__ float rexp2(float x) {   // q in [-1,0]: raw op safe
    float r; asm("v_exp_f32 %0, %1" : "=v"(r) : "v"(x)); return r;
}

#define SB0   __builtin_amdgcn_sched_barrier(0)
#define BAR   __builtin_amdgcn_s_barrier()
#define VMC4  asm volatile("s_waitcnt vmcnt(4)" ::: "memory")
#define LGKM0 asm volatile("s_waitcnt lgkmcnt(0)" ::: "memory")

// ---- pure pack: bf16 + row sumsq + col partial sums (no handshake) ----
// 1024 blocks x 256 thr, 8 rows each: 4 blocks/CU for HBM-latency MLP.
__global__ __launch_bounds__(256) void k_pack(const float* __restrict__ src,
        const float* __restrict__ tgt, ushort* __restrict__ P,
        float* __restrict__ sq, float* __restrict__ colpart,
        double* __restrict__ sqd) {
    __shared__ float  colred[4][256];
    __shared__ double sblk[4];
    int tid = threadIdx.x, w = tid >> 6, l = tid & 63;
    int blk = blockIdx.x;                       // 1024 blocks x 8 rows
    float c0 = 0.f, c1 = 0.f, c2 = 0.f, c3 = 0.f;
    double sacc = 0.0;
#pragma unroll
    for (int j = 0; j < 2; ++j) {
        int row = (blk << 3) + (j << 2) + w;
        const float* base = (row < N_HALF) ? src + (size_t)row * K_DIM
                                           : tgt + (size_t)(row - N_HALF) * K_DIM;
        float4 v = *(const float4*)(base + (l << 2));
        __hip_bfloat16 b0 = __float2bfloat16(v.x), b1 = __float2bfloat16(v.y),
                       b2 = __float2bfloat16(v.z), b3 = __float2bfloat16(v.w);
        ushort4 hv = { *(ushort*)&b0, *(ushort*)&b1, *(ushort*)&b2, *(ushort*)&b3 };
        *(ushort4*)(P + (size_t)row * K_DIM + (l << 2)) = hv;
        float s = v.x * v.x + v.y * v.y + v.z * v.z + v.w * v.w;
#pragma unroll
        for (int off = 32; off > 0; off >>= 1) s += __shfl_down(s, off, 64);
        if (l == 0) { sq[row] = s; sacc += (double)s; }
        c0 += v.x; c1 += v.y; c2 += v.z; c3 += v.w;
    }
    *(float4*)&colred[w][l << 2] = make_float4(c0, c1, c2, c3);
    if (l == 0) sblk[w] = sacc;
    __syncthreads();
    colpart[(blk << 8) + tid] = colred[0][tid] + colred[1][tid] +
                                colred[2][tid] + colred[3][tid];
    if (tid == 0)
        sqd[blk] = sblk[0] + sblk[1] + sblk[2] + sblk[3];
}

// ---- stage-1 column reduce: colpart[1024][256] -> colsd[32][256] (f64) ----
__global__ __launch_bounds__(256) void k_cred(const float* __restrict__ colpart,
                                              double* __restrict__ colsd) {
    int c = threadIdx.x;                // column
    int i = blockIdx.x;                 // row group: 32 rows
    int r0 = i << 5;
    double e0 = 0.0, e1 = 0.0, e2 = 0.0, e3 = 0.0;
#pragma unroll
    for (int r = 0; r < 32; r += 4) {
        e0 += (double)colpart[((r0 + r + 0) << 8) + c];
        e1 += (double)colpart[((r0 + r + 1) << 8) + c];
        e2 += (double)colpart[((r0 + r + 2) << 8) + c];
        e3 += (double)colpart[((r0 + r + 3) << 8) + c];
    }
    colsd[(i << 8) + c] = (e0 + e1) + (e2 + e3);
}

// ---- stage-2: Stot + ||colsum||^2 -> bandwidth ----
__global__ __launch_bounds__(512) void k_stats(const double* __restrict__ sqd,
        const double* __restrict__ colsd, double* __restrict__ band) {
    __shared__ double dred[512];
    __shared__ double dcol[2][256];
    int tid = threadIdx.x;
    // Stot over sqd[1024]
    dred[tid] = sqd[tid] + sqd[tid + 512];
    __syncthreads();
    for (int off = 256; off > 0; off >>= 1) {
        if (tid < off) dred[tid] += dred[tid + off];
        __syncthreads();
    }
    double Stot = dred[0];
    __syncthreads();
    // colsum: col = tid&255, half h = tid>>8 sums 16 of the 32 groups
    int c = tid & 255, h = tid >> 8;
    double e0 = 0.0, e1 = 0.0, e2 = 0.0, e3 = 0.0;
#pragma unroll
    for (int i = 0; i < 16; i += 4) {
        e0 += colsd[(((h << 4) + i + 0) << 8) + c];
        e1 += colsd[(((h << 4) + i + 1) << 8) + c];
        e2 += colsd[(((h << 4) + i + 2) << 8) + c];
        e3 += colsd[(((h << 4) + i + 3) << 8) + c];
    }
    dcol[h][c] = (e0 + e1) + (e2 + e3);
    __syncthreads();
    dred[tid] = 0.0;
    if (tid < 256) {
        double f = dcol[0][tid] + dcol[1][tid];
        dred[tid] = f * f;
    }
    __syncthreads();
    for (int off = 256; off > 0; off >>= 1) {
        if (tid < off) dred[tid] += dred[tid + off];
        __syncthreads();
    }
    if (tid == 0) {
        double sum_d2 = 2.0 * (double)M_TOT * Stot - 2.0 * dred[0];
        double bw = sum_d2 / ((double)M_TOT * (double)M_TOT - (double)M_TOT);
        *band = bw * 0.25;
    }
}

// triangle decode over 64x64 grid: t -> (bi, bj), bi <= bj
__device__ __forceinline__ void tri_decode(int t, int& bi, int& bj) {
    int x = (int)(64.5 - sqrt(64.5 * 64.5 - 2.0 * (double)t));
    while (x * 64 - x * (x - 1) / 2 > t) --x;
    while ((x + 1) * 64 - (x + 1) * x / 2 <= t) ++x;
    bi = x; bj = x + (t - (x * 64 - x * (x - 1) / 2));
}

// stage one 128x64 panel (16 KB): 2 gload16 per thread
__device__ __forceinline__ void stagePanel(const ushort* srcbase, size_t soff,
                                           char* ldsbase, int ldst) {
#pragma unroll
    for (int p = 0; p < 2; ++p)
        gload16(srcbase + soff + ((size_t)(p << 6) * K_DIM),
                ldsbase + (p << 13) + ldst);
}

// one K-tile of compute: 2 kk sub-phases x (6 ds_read_b128 + 8 MFMA)
__device__ __forceinline__ void computeTile(const ushort (&A)[128][64],
        const ushort (&B)[128][64], const int (&aoff)[4], const int (&boff)[2],
        f32x4 (&acc)[4][2]) {
#pragma unroll
    for (int kk = 0; kk < 2; ++kk) {
        short8 af[4], bf[2];
#pragma unroll
        for (int mt = 0; mt < 4; ++mt)
            af[mt] = *(const short8*)((const char*)&A[0][0] + (aoff[mt] ^ (kk << 6)));
#pragma unroll
        for (int nt = 0; nt < 2; ++nt)
            bf[nt] = *(const short8*)((const char*)&B[0][0] + (boff[nt] ^ (kk << 6)));
        __builtin_amdgcn_s_setprio(1);
#pragma unroll
        for (int mt = 0; mt < 4; ++mt)
#pragma unroll
            for (int nt = 0; nt < 2; ++nt)
                acc[mt][nt] = __builtin_amdgcn_mfma_f32_16x16x32_bf16(
                    af[mt], bf[nt], acc[mt][nt], 0, 0, 0);
        __builtin_amdgcn_s_setprio(0);
    }
}

// ---- persistent fused MFMA: 512 blocks x 4-5 tiles, continuous pipeline ----
// (verbatim R12/R17/R20 structure: best measured k_mmd = 43-50 us)
__global__ __launch_bounds__(512, 4) void k_mmd(const ushort* __restrict__ P,
        const float* __restrict__ sq, const double* __restrict__ band,
        double* __restrict__ parts, unsigned int* __restrict__ cnt,
        float* __restrict__ out) {
    __shared__ ushort As[2][128][64];
    __shared__ ushort Bs[2][128][64];

    int b = blockIdx.x;
    int xcd = b & 7, jj = b >> 3;
    int ntiles = (jj < 4) ? 5 : 4;     // 260 tiles per XCD = 4*64 + 4

    int tid = threadIdx.x, lane = tid & 63, w = tid >> 6;
    int wr = w >> 2, wc = w & 3;       // 2 x 4 wave grid, wave-tile 64x32

    int cx = ((lane >> 4) ^ (lane & 7)) << 4;
    int aoff[4], boff[2];
#pragma unroll
    for (int mt = 0; mt < 4; ++mt)
        aoff[mt] = (((wr << 6) + (mt << 4) + (lane & 15)) << 7) + cx;
#pragma unroll
    for (int nt = 0; nt < 2; ++nt)
        boff[nt] = (((wc << 5) + (nt << 4) + (lane & 15)) << 7) + cx;

    size_t soff = (size_t)(tid >> 3) * K_DIM
                + (((tid & 7) ^ ((tid >> 3) & 7)) << 3);
    int ldst = tid << 4;

    double bwd = *band;                       // oldest vmem; drained early
    float E16 = (float)(1.4426950408889634 / (bwd * 16.0));
    float twoE16 = 2.f * E16;

    int cbi, cbj;
    tri_decode(xcd * 260 + jj, cbi, cbj);
    int row0 = cbi << 7, col0 = cbj << 7;
    const ushort* Pa = P + (size_t)row0 * K_DIM;
    const ushort* Pb = P + (size_t)col0 * K_DIM;

    f32x4 acc[4][2] = {};
    double bsum = 0.0;

    stagePanel(Pa,      soff, (char*)&As[0][0][0], ldst);
    stagePanel(Pb,      soff, (char*)&Bs[0][0][0], ldst);
    stagePanel(Pa + 64, soff, (char*)&As[1][0][0], ldst);
    stagePanel(Pb + 64, soff, (char*)&Bs[1][0][0], ldst);

    for (int k = 0; k < ntiles; ++k) {
        bool more = (k + 1 < ntiles);
        SB0; VMC4; SB0; BAR; SB0;
        computeTile(As[0], Bs[0], aoff, boff, acc);
        SB0; LGKM0; SB0; BAR; SB0;
        stagePanel(Pa + 128, soff, (char*)&As[0][0][0], ldst);
        stagePanel(Pb + 128, soff, (char*)&Bs[0][0][0], ldst);
        SB0; VMC4; SB0; BAR; SB0;
        computeTile(As[1], Bs[1], aoff, boff, acc);
        SB0; LGKM0; SB0; BAR; SB0;
        stagePanel(Pa + 192, soff, (char*)&As[1][0][0], ldst);
        stagePanel(Pb + 192, soff, (char*)&Bs[1][0][0], ldst);
        SB0; VMC4; SB0; BAR; SB0;
        computeTile(As[0], Bs[0], aoff, boff, acc);
        SB0; LGKM0; SB0; BAR; SB0;
        // current-tile sq loads (retire before next-tile stages, in-order)
        float4 sv[4]; float bv0, bv1;
#pragma unroll
        for (int mt = 0; mt < 4; ++mt)
            sv[mt] = *(const float4*)&sq[row0 + (wr << 6) + (mt << 4) +
                                         ((lane >> 4) << 2)];
        bv0 = sq[col0 + (wc << 5) + (lane & 15)];
        bv1 = sq[col0 + (wc << 5) + 16 + (lane & 15)];
        int nbi = cbi, nbj = cbj, nrow0 = row0, ncol0 = col0;
        const ushort *nPa = Pa, *nPb = Pb;
        if (more) {
            tri_decode(xcd * 260 + jj + ((k + 1) << 6), nbi, nbj);
            nrow0 = nbi << 7; ncol0 = nbj << 7;
            nPa = P + (size_t)nrow0 * K_DIM;
            nPb = P + (size_t)ncol0 * K_DIM;
            stagePanel(nPa, soff, (char*)&As[0][0][0], ldst);
            stagePanel(nPb, soff, (char*)&Bs[0][0][0], ldst);
        }
        SB0; VMC4; SB0; BAR; SB0;
        computeTile(As[1], Bs[1], aoff, boff, acc);
        SB0; LGKM0; SB0; BAR; SB0;
        if (more) {
            stagePanel(nPa + 64, soff, (char*)&As[1][0][0], ldst);
            stagePanel(nPb + 64, soff, (char*)&Bs[1][0][0], ldst);
        }
        // epilogue (overlaps next tile's in-flight loads)
        bool isdiag = (cbi == cbj);
        float p0 = 0.f, p1 = 0.f, p2 = 0.f, p3 = 0.f, p4 = 0.f;
#pragma unroll
        for (int mt = 0; mt < 4; ++mt) {
            float A4[4] = { -sv[mt].x * E16, -sv[mt].y * E16,
                            -sv[mt].z * E16, -sv[mt].w * E16 };
            int rlb = (wr << 6) + (mt << 4) + ((lane >> 4) << 2);
#pragma unroll
            for (int nt = 0; nt < 2; ++nt) {
                float bvn = -(nt ? bv1 : bv0) * E16;
                int cl = (wc << 5) + (nt << 4) + (lane & 15);
#pragma unroll
                for (int j = 0; j < 4; ++j) {
                    float q = fmaf(acc[mt][nt][j], twoE16, A4[j] + bvn);
                    if (isdiag && (rlb + j == cl)) q = 0.f;
                    float t4 = rexp2(q);
                    float t3 = t4 * t4, t2 = t3 * t3, t1 = t2 * t2, t0 = t1 * t1;
                    p4 += t4; p3 += t3; p2 += t2; p1 += t1; p0 += t0;
                }
            }
        }
        float part = (p0 + p1) + (p2 + p3) + p4;
        float sgn = ((row0 < N_HALF) == (col0 < N_HALF)) ? 1.f : -1.f;
        float wt  = isdiag ? 1.f : 2.f;
        bsum += (double)part * (double)(sgn * wt);
#pragma unroll
        for (int mt = 0; mt < 4; ++mt)
#pragma unroll
            for (int nt = 0; nt < 2; ++nt)
                acc[mt][nt] = (f32x4){0.f, 0.f, 0.f, 0.f};
        cbi = nbi; cbj = nbj; row0 = nrow0; col0 = ncol0; Pa = nPa; Pb = nPb;
    }

    // wave reduce bsum (double)
#pragma unroll
    for (int off = 32; off > 0; off >>= 1) bsum += __shfl_down(bsum, off, 64);

    __syncthreads();                    // LDS dead: reuse
    double* wpart = (double*)&As[0][0][0];
    int*    lastf = (int*)((char*)&As[0][0][0] + 128);
    double* dredm = (double*)&Bs[0][0][0];

    if (lane == 0) wpart[w] = bsum;
    __syncthreads();
    if (tid == 0) {
        double tot = 0.0;
#pragma unroll
        for (int i = 0; i < 8; ++i) tot += wpart[i];
        parts[b] = tot;
        __threadfence();
        unsigned int o = atomicAdd(cnt, 1u);
        *lastf = (o == NBLK - 1u);
    }
    __syncthreads();
    if (*lastf) {                      // last block: reduce all partials
        __threadfence();
        dredm[tid] = parts[tid];
        __syncthreads();
        for (int off = 256; off > 0; off >>= 1) {
            if (tid < off) dredm[tid] += dredm[tid + off];
            __syncthreads();
        }
        if (tid == 0)
            out[0] = (float)(dredm[0] * (1.0 / ((double)N_HALF * (double)N_HALF)));
    }
}

extern "C" void kernel_launch(void* const* d_in, const int* in_sizes, int n_in,
                              void* d_out, int out_size, void* d_ws, size_t ws_size,
                              hipStream_t stream) {
    const float* src = (const float*)d_in[0];
    const float* tgt = (const float*)d_in[1];
    float*  sq      = (float*)((char*)d_ws + WS_SQ);
    float*  colpart = (float*)((char*)d_ws + WS_COLPART);
    double* sqd     = (double*)((char*)d_ws + WS_SQD);
    double* colsd   = (double*)((char*)d_ws + WS_COLSD);
    double* band    = (double*)((char*)d_ws + WS_BAND);
    unsigned int* cnt = (unsigned int*)((char*)d_ws + WS_CNT);
    double* parts   = (double*)((char*)d_ws + WS_PARTS);
    ushort* P       = (ushort*)((char*)d_ws + WS_P);

    hipMemsetAsync((char*)d_ws + WS_BAND, 0, 64, stream);
    k_pack <<<NPACK, 256, 0, stream>>>(src, tgt, P, sq, colpart, sqd);
    k_cred <<<32,    256, 0, stream>>>(colpart, colsd);
    k_stats<<<1,     512, 0, stream>>>(sqd, colsd, band);
    k_mmd  <<<NBLK,  512, 0, stream>>>(P, sq, band, parts, cnt, (float*)d_out);
}

// Round 23
// 61.357 us; speedup vs baseline: 1.8807x; 1.0624x over previous
//
#include <hip/hip_runtime.h>
#include <hip/hip_bf16.h>

#define N_HALF 4096
#define M_TOT  8192
#define K_DIM  256
#define NBLK   512     // persistent mmd blocks (2 per CU)
#define NPACK  1024    // pack blocks (4 per CU)

// ws layout (bytes)
#define WS_SQ      0                       // 8192 f32 (32 KB)
#define WS_COLPART 32768                   // 1024*256 f32 (1 MB)
#define WS_SQD     1081344                 // 1024 f64 (8 KB)
#define WS_COLSD   1089536                 // 32*256 f64 (64 KB)
#define WS_BAND    1155072                 // f64
#define WS_CNT     1155080                 // u32 (k_mmd completion)
#define WS_PARTS   1155136                 // 512 f64 (4 KB)
#define WS_P       1159232                 // 8192*256 bf16 = 4 MB

typedef __attribute__((ext_vector_type(8))) short short8;
typedef __attribute__((ext_vector_type(4))) float f32x4;

__device__ __forceinline__ void gload16(const void* g, void* l) {
    __builtin_amdgcn_global_load_lds(
        (const __attribute__((address_space(1))) void*)g,
        (__attribute__((address_space(3))) void*)l, 16, 0, 0);
}

__device__ __forceinline__ float rexp2(float x) {   // q in [-1,0]: raw op safe
    float r; asm("v_exp_f32 %0, %1" : "=v"(r) : "v"(x)); return r;
}

#define SB0   __builtin_amdgcn_sched_barrier(0)
#define BAR   __builtin_amdgcn_s_barrier()
#define VMC4  asm volatile("s_waitcnt vmcnt(4)" ::: "memory")
#define LGKM0 asm volatile("s_waitcnt lgkmcnt(0)" ::: "memory")

// ---- pure pack: bf16 + row sumsq + col partial sums (no handshake) ----
__global__ __launch_bounds__(256) void k_pack(const float* __restrict__ src,
        const float* __restrict__ tgt, ushort* __restrict__ P,
        float* __restrict__ sq, float* __restrict__ colpart,
        double* __restrict__ sqd) {
    __shared__ float  colred[4][256];
    __shared__ double sblk[4];
    int tid = threadIdx.x, w = tid >> 6, l = tid & 63;
    int blk = blockIdx.x;                       // 1024 blocks x 8 rows
    float c0 = 0.f, c1 = 0.f, c2 = 0.f, c3 = 0.f;
    double sacc = 0.0;
#pragma unroll
    for (int j = 0; j < 2; ++j) {
        int row = (blk << 3) + (j << 2) + w;
        const float* base = (row < N_HALF) ? src + (size_t)row * K_DIM
                                           : tgt + (size_t)(row - N_HALF) * K_DIM;
        float4 v = *(const float4*)(base + (l << 2));
        __hip_bfloat16 b0 = __float2bfloat16(v.x), b1 = __float2bfloat16(v.y),
                       b2 = __float2bfloat16(v.z), b3 = __float2bfloat16(v.w);
        ushort4 hv = { *(ushort*)&b0, *(ushort*)&b1, *(ushort*)&b2, *(ushort*)&b3 };
        *(ushort4*)(P + (size_t)row * K_DIM + (l << 2)) = hv;
        float s = v.x * v.x + v.y * v.y + v.z * v.z + v.w * v.w;
#pragma unroll
        for (int off = 32; off > 0; off >>= 1) s += __shfl_down(s, off, 64);
        if (l == 0) { sq[row] = s; sacc += (double)s; }
        c0 += v.x; c1 += v.y; c2 += v.z; c3 += v.w;
    }
    *(float4*)&colred[w][l << 2] = make_float4(c0, c1, c2, c3);
    if (l == 0) sblk[w] = sacc;
    __syncthreads();
    colpart[(blk << 8) + tid] = colred[0][tid] + colred[1][tid] +
                                colred[2][tid] + colred[3][tid];
    if (tid == 0)
        sqd[blk] = sblk[0] + sblk[1] + sblk[2] + sblk[3];
}

// ---- stage-1 column reduce: colpart[1024][256] -> colsd[32][256] (f64) ----
__global__ __launch_bounds__(256) void k_cred(const float* __restrict__ colpart,
                                              double* __restrict__ colsd) {
    int c = threadIdx.x;                // column
    int i = blockIdx.x;                 // row group: 32 rows
    int r0 = i << 5;
    double e0 = 0.0, e1 = 0.0, e2 = 0.0, e3 = 0.0;
#pragma unroll
    for (int r = 0; r < 32; r += 4) {
        e0 += (double)colpart[((r0 + r + 0) << 8) + c];
        e1 += (double)colpart[((r0 + r + 1) << 8) + c];
        e2 += (double)colpart[((r0 + r + 2) << 8) + c];
        e3 += (double)colpart[((r0 + r + 3) << 8) + c];
    }
    colsd[(i << 8) + c] = (e0 + e1) + (e2 + e3);
}

// ---- stage-2: Stot + ||colsum||^2 -> bandwidth; also zeroes cnt ----
__global__ __launch_bounds__(512) void k_stats(const double* __restrict__ sqd,
        const double* __restrict__ colsd, double* __restrict__ band,
        unsigned int* __restrict__ cnt) {
    __shared__ double dred[512];
    __shared__ double dcol[2][256];
    int tid = threadIdx.x;
    if (tid == 0) *cnt = 0u;            // replaces hipMemsetAsync (stream-ordered)
    // Stot over sqd[1024]
    dred[tid] = sqd[tid] + sqd[tid + 512];
    __syncthreads();
    for (int off = 256; off > 0; off >>= 1) {
        if (tid < off) dred[tid] += dred[tid + off];
        __syncthreads();
    }
    double Stot = dred[0];
    __syncthreads();
    // colsum: col = tid&255, half h = tid>>8 sums 16 of the 32 groups
    int c = tid & 255, h = tid >> 8;
    double e0 = 0.0, e1 = 0.0, e2 = 0.0, e3 = 0.0;
#pragma unroll
    for (int i = 0; i < 16; i += 4) {
        e0 += colsd[(((h << 4) + i + 0) << 8) + c];
        e1 += colsd[(((h << 4) + i + 1) << 8) + c];
        e2 += colsd[(((h << 4) + i + 2) << 8) + c];
        e3 += colsd[(((h << 4) + i + 3) << 8) + c];
    }
    dcol[h][c] = (e0 + e1) + (e2 + e3);
    __syncthreads();
    dred[tid] = 0.0;
    if (tid < 256) {
        double f = dcol[0][tid] + dcol[1][tid];
        dred[tid] = f * f;
    }
    __syncthreads();
    for (int off = 256; off > 0; off >>= 1) {
        if (tid < off) dred[tid] += dred[tid + off];
        __syncthreads();
    }
    if (tid == 0) {
        double sum_d2 = 2.0 * (double)M_TOT * Stot - 2.0 * dred[0];
        double bw = sum_d2 / ((double)M_TOT * (double)M_TOT - (double)M_TOT);
        *band = bw * 0.25;
    }
}

// triangle decode over 64x64 grid: t -> (bi, bj), bi <= bj
__device__ __forceinline__ void tri_decode(int t, int& bi, int& bj) {
    int x = (int)(64.5 - sqrt(64.5 * 64.5 - 2.0 * (double)t));
    while (x * 64 - x * (x - 1) / 2 > t) --x;
    while ((x + 1) * 64 - (x + 1) * x / 2 <= t) ++x;
    bi = x; bj = x + (t - (x * 64 - x * (x - 1) / 2));
}

// stage one 128x64 panel (16 KB): 2 gload16 per thread
__device__ __forceinline__ void stagePanel(const ushort* srcbase, size_t soff,
                                           char* ldsbase, int ldst) {
#pragma unroll
    for (int p = 0; p < 2; ++p)
        gload16(srcbase + soff + ((size_t)(p << 6) * K_DIM),
                ldsbase + (p << 13) + ldst);
}

// one K-tile of compute: 2 kk sub-phases x (6 ds_read_b128 + 8 MFMA)
__device__ __forceinline__ void computeTile(const ushort (&A)[128][64],
        const ushort (&B)[128][64], const int (&aoff)[4], const int (&boff)[2],
        f32x4 (&acc)[4][2]) {
#pragma unroll
    for (int kk = 0; kk < 2; ++kk) {
        short8 af[4], bf[2];
#pragma unroll
        for (int mt = 0; mt < 4; ++mt)
            af[mt] = *(const short8*)((const char*)&A[0][0] + (aoff[mt] ^ (kk << 6)));
#pragma unroll
        for (int nt = 0; nt < 2; ++nt)
            bf[nt] = *(const short8*)((const char*)&B[0][0] + (boff[nt] ^ (kk << 6)));
        __builtin_amdgcn_s_setprio(1);
#pragma unroll
        for (int mt = 0; mt < 4; ++mt)
#pragma unroll
            for (int nt = 0; nt < 2; ++nt)
                acc[mt][nt] = __builtin_amdgcn_mfma_f32_16x16x32_bf16(
                    af[mt], bf[nt], acc[mt][nt], 0, 0, 0);
        __builtin_amdgcn_s_setprio(0);
    }
}

// ---- persistent fused MFMA: 512 blocks x 4-5 tiles, continuous pipeline ----
// (verbatim R12/R17/R20 structure: best measured k_mmd = 43-50 us)
__global__ __launch_bounds__(512, 4) void k_mmd(const ushort* __restrict__ P,
        const float* __restrict__ sq, const double* __restrict__ band,
        double* __restrict__ parts, unsigned int* __restrict__ cnt,
        float* __restrict__ out) {
    __shared__ ushort As[2][128][64];
    __shared__ ushort Bs[2][128][64];

    int b = blockIdx.x;
    int xcd = b & 7, jj = b >> 3;
    int ntiles = (jj < 4) ? 5 : 4;     // 260 tiles per XCD = 4*64 + 4

    int tid = threadIdx.x, lane = tid & 63, w = tid >> 6;
    int wr = w >> 2, wc = w & 3;       // 2 x 4 wave grid, wave-tile 64x32

    int cx = ((lane >> 4) ^ (lane & 7)) << 4;
    int aoff[4], boff[2];
#pragma unroll
    for (int mt = 0; mt < 4; ++mt)
        aoff[mt] = (((wr << 6) + (mt << 4) + (lane & 15)) << 7) + cx;
#pragma unroll
    for (int nt = 0; nt < 2; ++nt)
        boff[nt] = (((wc << 5) + (nt << 4) + (lane & 15)) << 7) + cx;

    size_t soff = (size_t)(tid >> 3) * K_DIM
                + (((tid & 7) ^ ((tid >> 3) & 7)) << 3);
    int ldst = tid << 4;

    double bwd = *band;                       // oldest vmem; drained early
    float E16 = (float)(1.4426950408889634 / (bwd * 16.0));
    float twoE16 = 2.f * E16;

    int cbi, cbj;
    tri_decode(xcd * 260 + jj, cbi, cbj);
    int row0 = cbi << 7, col0 = cbj << 7;
    const ushort* Pa = P + (size_t)row0 * K_DIM;
    const ushort* Pb = P + (size_t)col0 * K_DIM;

    f32x4 acc[4][2] = {};
    double bsum = 0.0;

    stagePanel(Pa,      soff, (char*)&As[0][0][0], ldst);
    stagePanel(Pb,      soff, (char*)&Bs[0][0][0], ldst);
    stagePanel(Pa + 64, soff, (char*)&As[1][0][0], ldst);
    stagePanel(Pb + 64, soff, (char*)&Bs[1][0][0], ldst);

    for (int k = 0; k < ntiles; ++k) {
        bool more = (k + 1 < ntiles);
        SB0; VMC4; SB0; BAR; SB0;
        computeTile(As[0], Bs[0], aoff, boff, acc);
        SB0; LGKM0; SB0; BAR; SB0;
        stagePanel(Pa + 128, soff, (char*)&As[0][0][0], ldst);
        stagePanel(Pb + 128, soff, (char*)&Bs[0][0][0], ldst);
        SB0; VMC4; SB0; BAR; SB0;
        computeTile(As[1], Bs[1], aoff, boff, acc);
        SB0; LGKM0; SB0; BAR; SB0;
        stagePanel(Pa + 192, soff, (char*)&As[1][0][0], ldst);
        stagePanel(Pb + 192, soff, (char*)&Bs[1][0][0], ldst);
        SB0; VMC4; SB0; BAR; SB0;
        computeTile(As[0], Bs[0], aoff, boff, acc);
        SB0; LGKM0; SB0; BAR; SB0;
        // current-tile sq loads (retire before next-tile stages, in-order)
        float4 sv[4]; float bv0, bv1;
#pragma unroll
        for (int mt = 0; mt < 4; ++mt)
            sv[mt] = *(const float4*)&sq[row0 + (wr << 6) + (mt << 4) +
                                         ((lane >> 4) << 2)];
        bv0 = sq[col0 + (wc << 5) + (lane & 15)];
        bv1 = sq[col0 + (wc << 5) + 16 + (lane & 15)];
        int nbi = cbi, nbj = cbj, nrow0 = row0, ncol0 = col0;
        const ushort *nPa = Pa, *nPb = Pb;
        if (more) {
            tri_decode(xcd * 260 + jj + ((k + 1) << 6), nbi, nbj);
            nrow0 = nbi << 7; ncol0 = nbj << 7;
            nPa = P + (size_t)nrow0 * K_DIM;
            nPb = P + (size_t)ncol0 * K_DIM;
            stagePanel(nPa, soff, (char*)&As[0][0][0], ldst);
            stagePanel(nPb, soff, (char*)&Bs[0][0][0], ldst);
        }
        SB0; VMC4; SB0; BAR; SB0;
        computeTile(As[1], Bs[1], aoff, boff, acc);
        SB0; LGKM0; SB0; BAR; SB0;
        if (more) {
            stagePanel(nPa + 64, soff, (char*)&As[1][0][0], ldst);
            stagePanel(nPb + 64, soff, (char*)&Bs[1][0][0], ldst);
        }
        // epilogue (overlaps next tile's in-flight loads)
        bool isdiag = (cbi == cbj);
        float p0 = 0.f, p1 = 0.f, p2 = 0.f, p3 = 0.f, p4 = 0.f;
#pragma unroll
        for (int mt = 0; mt < 4; ++mt) {
            float A4[4] = { -sv[mt].x * E16, -sv[mt].y * E16,
                            -sv[mt].z * E16, -sv[mt].w * E16 };
            int rlb = (wr << 6) + (mt << 4) + ((lane >> 4) << 2);
#pragma unroll
            for (int nt = 0; nt < 2; ++nt) {
                float bvn = -(nt ? bv1 : bv0) * E16;
                int cl = (wc << 5) + (nt << 4) + (lane & 15);
#pragma unroll
                for (int j = 0; j < 4; ++j) {
                    float q = fmaf(acc[mt][nt][j], twoE16, A4[j] + bvn);
                    if (isdiag && (rlb + j == cl)) q = 0.f;
                    float t4 = rexp2(q);
                    float t3 = t4 * t4, t2 = t3 * t3, t1 = t2 * t2, t0 = t1 * t1;
                    p4 += t4; p3 += t3; p2 += t2; p1 += t1; p0 += t0;
                }
            }
        }
        float part = (p0 + p1) + (p2 + p3) + p4;
        float sgn = ((row0 < N_HALF) == (col0 < N_HALF)) ? 1.f : -1.f;
        float wt  = isdiag ? 1.f : 2.f;
        bsum += (double)part * (double)(sgn * wt);
#pragma unroll
        for (int mt = 0; mt < 4; ++mt)
#pragma unroll
            for (int nt = 0; nt < 2; ++nt)
                acc[mt][nt] = (f32x4){0.f, 0.f, 0.f, 0.f};
        cbi = nbi; cbj = nbj; row0 = nrow0; col0 = ncol0; Pa = nPa; Pb = nPb;
    }

    // wave reduce bsum (double)
#pragma unroll
    for (int off = 32; off > 0; off >>= 1) bsum += __shfl_down(bsum, off, 64);

    __syncthreads();                    // LDS dead: reuse
    double* wpart = (double*)&As[0][0][0];
    int*    lastf = (int*)((char*)&As[0][0][0] + 128);
    double* dredm = (double*)&Bs[0][0][0];

    if (lane == 0) wpart[w] = bsum;
    __syncthreads();
    if (tid == 0) {
        double tot = 0.0;
#pragma unroll
        for (int i = 0; i < 8; ++i) tot += wpart[i];
        parts[b] = tot;
        __threadfence();
        unsigned int o = atomicAdd(cnt, 1u);
        *lastf = (o == NBLK - 1u);
    }
    __syncthreads();
    if (*lastf) {                      // last block: reduce all partials
        __threadfence();
        dredm[tid] = parts[tid];
        __syncthreads();
        for (int off = 256; off > 0; off >>= 1) {
            if (tid < off) dredm[tid] += dredm[tid + off];
            __syncthreads();
        }
        if (tid == 0)
            out[0] = (float)(dredm[0] * (1.0 / ((double)N_HALF * (double)N_HALF)));
    }
}

extern "C" void kernel_launch(void* const* d_in, const int* in_sizes, int n_in,
                              void* d_out, int out_size, void* d_ws, size_t ws_size,
                              hipStream_t stream) {
    const float* src = (const float*)d_in[0];
    const float* tgt = (const float*)d_in[1];
    float*  sq      = (float*)((char*)d_ws + WS_SQ);
    float*  colpart = (float*)((char*)d_ws + WS_COLPART);
    double* sqd     = (double*)((char*)d_ws + WS_SQD);
    double* colsd   = (double*)((char*)d_ws + WS_COLSD);
    double* band    = (double*)((char*)d_ws + WS_BAND);
    unsigned int* cnt = (unsigned int*)((char*)d_ws + WS_CNT);
    double* parts   = (double*)((char*)d_ws + WS_PARTS);
    ushort* P       = (ushort*)((char*)d_ws + WS_P);

    k_pack <<<NPACK, 256, 0, stream>>>(src, tgt, P, sq, colpart, sqd);
    k_cred <<<32,    256, 0, stream>>>(colpart, colsd);
    k_stats<<<1,     512, 0, stream>>>(sqd, colsd, band, cnt);
    k_mmd  <<<NBLK,  512, 0, stream>>>(P, sq, band, parts, cnt, (float*)d_out);
}